// Round 4
// baseline (95.764 us; speedup 1.0000x reference)
//
#include <hip/hip_runtime.h>
#include <math.h>

// LDDMM variational RHS, Gaussian kernel sigma=0.1, B=1, N=8192, D=3.
// out[0:N*3]     = dmom_i = (1/sig^2) * (x_i * sum_j W_ij - sum_j W_ij x_j)
// out[N*3:2*N*3] = dcp_i  = sum_j K_ij p_j
// K_ij = exp(-|x_i-x_j|^2/(2 sig^2)), W_ij = K_ij*(p_i.p_j), p=clamp(mom,-1,1)
//
// R4: kill LDS entirely. R2 matched the per-CU LDS-pipe model (98k cy = 41us)
// and R3's halved LDS demand didn't materialize as a win -> the broadcast
// ds_read path + staging/sync is the constraint. j-indices are wave-uniform,
// so reading a pre-packed 32B/point jd[] array compiles to s_load_dwordx8
// (scalar pipe, free) and v_fma with one SGPR operand -- no LDS, no
// __syncthreads. Prep kernel hoists clamp + COEF*|x|^2 out of the 67M-pair
// loop. Expected partial ~15us (VALU-bound: 32 VALU + 2 exp per wave-iter).

#define NPTS 8192
#define N3   (NPTS * 3)
#define BI   256
#define MI   2                       // i-points per thread
#define IBLK (NPTS / (BI * MI))      // 16 i-blocks
#define JC   64
#define JLEN (NPTS / JC)             // 128

// exp(-d2/(2*0.1^2)) = exp2(d2 * (-50*log2(e)))
#define COEF   (-72.134752044448170f)
#define M2COEF (144.269504088896340f)   // -2*COEF

// ws layout: [0, JC*NPTS*8) chunk partials; [JD_OFF, JD_OFF+NPTS*8) packed j-data
#define JD_OFF    ((size_t)JC * NPTS * 8)
#define WS_NEEDED ((JD_OFF + (size_t)NPTS * 8) * sizeof(float))   // ~17.0 MB

__device__ __forceinline__ float fast_exp2(float x) {
#if __has_builtin(__builtin_amdgcn_exp2f)
    return __builtin_amdgcn_exp2f(x);
#else
    return exp2f(x);
#endif
}

__device__ __forceinline__ float clamp1(float v) {
    return fminf(fmaxf(v, -1.0f), 1.0f);
}

// jd[j*8 + 0..7] = {x0, x1, x2, COEF*|x|^2, p0c, p1c, p2c, 0}
__global__ __launch_bounds__(256) void lddmm_prep(const float* __restrict__ mom,
                                                  const float* __restrict__ cp,
                                                  float* __restrict__ jd) {
    const int j = (int)blockIdx.x * 256 + (int)threadIdx.x;
    const float x0 = cp[j * 3 + 0], x1 = cp[j * 3 + 1], x2 = cp[j * 3 + 2];
    const float cj = COEF * (x0 * x0 + x1 * x1 + x2 * x2);
    float4* o = (float4*)(jd + (size_t)j * 8);
    o[0] = make_float4(x0, x1, x2, cj);
    o[1] = make_float4(clamp1(mom[j * 3 + 0]), clamp1(mom[j * 3 + 1]),
                       clamp1(mom[j * 3 + 2]), 0.0f);
}

// chunk partials: ws[((c*NPTS)+i)*8 + k], k=0..3: dcp,wsum; 4..7: wx,0
__global__ __launch_bounds__(BI) void lddmm_partial(const float* __restrict__ jd,
                                                    float* __restrict__ ws) {
    const int ib = (int)blockIdx.x / JC;
    const int jc = (int)blockIdx.x % JC;
    const int t  = (int)threadIdx.x;
    const int i0 = ib * (BI * MI) + t;
    const int i1 = i0 + BI;

    // i-side data from the packed array (prep ran first on this stream)
    const float4 xa4 = ((const float4*)(jd + (size_t)i0 * 8))[0];
    const float4 pa4 = ((const float4*)(jd + (size_t)i0 * 8))[1];
    const float4 xb4 = ((const float4*)(jd + (size_t)i1 * 8))[0];
    const float4 pb4 = ((const float4*)(jd + (size_t)i1 * 8))[1];
    const float xa0 = xa4.x, xa1 = xa4.y, xa2 = xa4.z, ca = xa4.w;
    const float pa0 = pa4.x, pa1 = pa4.y, pa2 = pa4.z;
    const float xb0 = xb4.x, xb1 = xb4.y, xb2 = xb4.z, cb = xb4.w;
    const float pb0 = pb4.x, pb1 = pb4.y, pb2 = pb4.z;

    float a_dcp0 = 0.f, a_dcp1 = 0.f, a_dcp2 = 0.f, a_ws = 0.f;
    float a_wx0 = 0.f, a_wx1 = 0.f, a_wx2 = 0.f;
    float b_dcp0 = 0.f, b_dcp1 = 0.f, b_dcp2 = 0.f, b_ws = 0.f;
    float b_wx0 = 0.f, b_wx1 = 0.f, b_wx2 = 0.f;

    const float* __restrict__ q = jd + (size_t)(jc * JLEN) * 8;

#pragma unroll 4
    for (int jj = 0; jj < JLEN; ++jj) {
        // wave-uniform index -> s_load_dwordx8; values live in SGPRs and feed
        // v_fma as the single allowed SGPR operand. No LDS, no sync.
        const float xj0 = q[jj * 8 + 0];
        const float xj1 = q[jj * 8 + 1];
        const float xj2 = q[jj * 8 + 2];
        const float cj  = q[jj * 8 + 3];
        const float pj0 = q[jj * 8 + 4];
        const float pj1 = q[jj * 8 + 5];
        const float pj2 = q[jj * 8 + 6];

        // i0
        float dota = xa0 * xj0;
        dota = fmaf(xa1, xj1, dota);
        dota = fmaf(xa2, xj2, dota);
        const float Ka = fast_exp2(fmaf(dota, M2COEF, ca + cj));
        float pda = pa0 * pj0;
        pda = fmaf(pa1, pj1, pda);
        pda = fmaf(pa2, pj2, pda);
        const float Wa = Ka * pda;
        a_dcp0 = fmaf(Ka, pj0, a_dcp0);
        a_dcp1 = fmaf(Ka, pj1, a_dcp1);
        a_dcp2 = fmaf(Ka, pj2, a_dcp2);
        a_ws += Wa;
        a_wx0 = fmaf(Wa, xj0, a_wx0);
        a_wx1 = fmaf(Wa, xj1, a_wx1);
        a_wx2 = fmaf(Wa, xj2, a_wx2);

        // i1
        float dotb = xb0 * xj0;
        dotb = fmaf(xb1, xj1, dotb);
        dotb = fmaf(xb2, xj2, dotb);
        const float Kb = fast_exp2(fmaf(dotb, M2COEF, cb + cj));
        float pdb = pb0 * pj0;
        pdb = fmaf(pb1, pj1, pdb);
        pdb = fmaf(pb2, pj2, pdb);
        const float Wb = Kb * pdb;
        b_dcp0 = fmaf(Kb, pj0, b_dcp0);
        b_dcp1 = fmaf(Kb, pj1, b_dcp1);
        b_dcp2 = fmaf(Kb, pj2, b_dcp2);
        b_ws += Wb;
        b_wx0 = fmaf(Wb, xj0, b_wx0);
        b_wx1 = fmaf(Wb, xj1, b_wx1);
        b_wx2 = fmaf(Wb, xj2, b_wx2);
    }

    float4* oa = (float4*)(ws + ((size_t)(jc * NPTS) + i0) * 8);
    oa[0] = make_float4(a_dcp0, a_dcp1, a_dcp2, a_ws);
    oa[1] = make_float4(a_wx0, a_wx1, a_wx2, 0.0f);
    float4* ob = (float4*)(ws + ((size_t)(jc * NPTS) + i1) * 8);
    ob[0] = make_float4(b_dcp0, b_dcp1, b_dcp2, b_ws);
    ob[1] = make_float4(b_wx0, b_wx1, b_wx2, 0.0f);
}

// 4 threads per i: sub=(cpart,half). Each sums JC/2 chunks of one float4,
// xor-2 combines chunk halves, xor-1 hands wsum from half0 to half1.
__global__ __launch_bounds__(256) void lddmm_reduce(const float* __restrict__ ws,
                                                    const float* __restrict__ cp,
                                                    float* __restrict__ out) {
    const int tid   = (int)blockIdx.x * 256 + (int)threadIdx.x;
    const int i     = tid >> 2;
    const int sub   = tid & 3;
    const int half  = sub & 1;
    const int cpart = sub >> 1;

    float4 acc = make_float4(0.f, 0.f, 0.f, 0.f);
    const int c0 = cpart * (JC / 2);
#pragma unroll 4
    for (int c = c0; c < c0 + JC / 2; ++c) {
        const float4 v = ((const float4*)(ws + ((size_t)(c * NPTS) + i) * 8))[half];
        acc.x += v.x; acc.y += v.y; acc.z += v.z; acc.w += v.w;
    }
    acc.x += __shfl_xor(acc.x, 2);
    acc.y += __shfl_xor(acc.y, 2);
    acc.z += __shfl_xor(acc.z, 2);
    acc.w += __shfl_xor(acc.w, 2);
    const float wsum = __shfl_xor(acc.w, 1);
    if (sub == 0) {
        out[N3 + i * 3 + 0] = acc.x;
        out[N3 + i * 3 + 1] = acc.y;
        out[N3 + i * 3 + 2] = acc.z;
    } else if (sub == 1) {
        const float xi0 = cp[i * 3 + 0];
        const float xi1 = cp[i * 3 + 1];
        const float xi2 = cp[i * 3 + 2];
        out[i * 3 + 0] = 100.0f * (xi0 * wsum - acc.x);
        out[i * 3 + 1] = 100.0f * (xi1 * wsum - acc.y);
        out[i * 3 + 2] = 100.0f * (xi2 * wsum - acc.z);
    }
}

// ---- fallback (atomics into d_out) if ws_size < WS_NEEDED ----
#define FJC   32
#define FJLEN (NPTS / FJC)
__global__ __launch_bounds__(BI) void lddmm_pairs_atomic(const float* __restrict__ mom,
                                                         const float* __restrict__ cp,
                                                         float* __restrict__ out) {
    const int ib = (int)blockIdx.x / FJC;
    const int jc = (int)blockIdx.x % FJC;
    const int t  = (int)threadIdx.x;
    const int i  = ib * BI + t;

    const float xi0 = cp[i * 3 + 0], xi1 = cp[i * 3 + 1], xi2 = cp[i * 3 + 2];
    const float pi0 = clamp1(mom[i * 3 + 0]), pi1 = clamp1(mom[i * 3 + 1]),
                pi2 = clamp1(mom[i * 3 + 2]);

    __shared__ float4 shx[FJLEN];
    __shared__ float4 shp[FJLEN];
    {
        const int j = jc * FJLEN + t;
        shx[t] = make_float4(cp[j * 3 + 0], cp[j * 3 + 1], cp[j * 3 + 2], 0.0f);
        shp[t] = make_float4(clamp1(mom[j * 3 + 0]), clamp1(mom[j * 3 + 1]),
                             clamp1(mom[j * 3 + 2]), 0.0f);
    }
    __syncthreads();

    float dcp0 = 0.f, dcp1 = 0.f, dcp2 = 0.f, wsum = 0.f, wx0 = 0.f, wx1 = 0.f, wx2 = 0.f;
#pragma unroll 4
    for (int jj = 0; jj < FJLEN; ++jj) {
        const float4 xj = shx[jj];
        const float4 pj = shp[jj];
        const float dx0 = xi0 - xj.x, dx1 = xi1 - xj.y, dx2 = xi2 - xj.z;
        const float d2  = dx0 * dx0 + dx1 * dx1 + dx2 * dx2;
        const float K   = fast_exp2(d2 * COEF);
        const float pd  = pi0 * pj.x + pi1 * pj.y + pi2 * pj.z;
        const float W   = K * pd;
        dcp0 += K * pj.x; dcp1 += K * pj.y; dcp2 += K * pj.z;
        wsum += W;
        wx0 += W * xj.x; wx1 += W * xj.y; wx2 += W * xj.z;
    }
    atomicAdd(&out[i * 3 + 0], 100.0f * (xi0 * wsum - wx0));
    atomicAdd(&out[i * 3 + 1], 100.0f * (xi1 * wsum - wx1));
    atomicAdd(&out[i * 3 + 2], 100.0f * (xi2 * wsum - wx2));
    atomicAdd(&out[N3 + i * 3 + 0], dcp0);
    atomicAdd(&out[N3 + i * 3 + 1], dcp1);
    atomicAdd(&out[N3 + i * 3 + 2], dcp2);
}

extern "C" void kernel_launch(void* const* d_in, const int* in_sizes, int n_in,
                              void* d_out, int out_size, void* d_ws, size_t ws_size,
                              hipStream_t stream) {
    const float* mom = (const float*)d_in[0];
    const float* cp  = (const float*)d_in[1];
    float* out = (float*)d_out;

    if (ws_size >= WS_NEEDED) {
        float* ws = (float*)d_ws;
        float* jd = ws + JD_OFF;
        hipLaunchKernelGGL(lddmm_prep, dim3(NPTS / 256), dim3(256), 0, stream, mom, cp, jd);
        hipLaunchKernelGGL(lddmm_partial, dim3(IBLK * JC), dim3(BI), 0, stream, jd, ws);
        hipLaunchKernelGGL(lddmm_reduce, dim3(NPTS * 4 / 256), dim3(256), 0, stream, ws, cp, out);
    } else {
        hipMemsetAsync(out, 0, (size_t)out_size * sizeof(float), stream);
        hipLaunchKernelGGL(lddmm_pairs_atomic, dim3((NPTS / BI) * FJC), dim3(BI), 0, stream, mom, cp, out);
    }
}